// Round 7
// baseline (702.604 us; speedup 1.0000x reference)
//
#include <hip/hip_runtime.h>
#include <hip/hip_bf16.h>

typedef __bf16 bf16;
typedef __bf16 bf16x8 __attribute__((ext_vector_type(8)));
typedef float f32x4 __attribute__((ext_vector_type(4)));
typedef unsigned char u8;
typedef unsigned int u32;
typedef unsigned short u16;
typedef u16 ushort8 __attribute__((ext_vector_type(8)));

#define B_ 4
#define T_ 1024
#define NX_ 1024
#define NH_ 16
#define HD_ 64

__device__ __forceinline__ void gld16(const void* g, void* l) {
  __builtin_amdgcn_global_load_lds((const __attribute__((address_space(1))) void*)g,
                                   (__attribute__((address_space(3))) void*)l, 16, 0, 0);
}

// ---------- prep: contiguous fp32 -> bf16 ----------
__global__ __launch_bounds__(256) void k_cvt(const float* __restrict__ in, bf16* __restrict__ out, int n) {
  int i = (blockIdx.x * 256 + threadIdx.x) * 4;
  if (i + 3 < n) {
    float4 v = *(const float4*)(in + i);
    out[i] = (bf16)v.x; out[i + 1] = (bf16)v.y; out[i + 2] = (bf16)v.z; out[i + 3] = (bf16)v.w;
  }
}

// ---------- prep: (K,N) f32 -> (N,K) bf16 transpose ----------
__global__ __launch_bounds__(256) void k_transpose(const float* __restrict__ in, bf16* __restrict__ out, int K, int N) {
  __shared__ float tile[64][65];
  int n0 = blockIdx.x * 64, k0 = blockIdx.y * 64;
  for (int i = threadIdx.x; i < 4096; i += 256) {
    int r = i >> 6, c = i & 63;
    tile[r][c] = in[(size_t)(k0 + r) * N + n0 + c];
  }
  __syncthreads();
  for (int i = threadIdx.x; i < 4096; i += 256) {
    int r = i >> 6, c = i & 63;
    out[(size_t)(n0 + r) * K + k0 + c] = (bf16)tile[c][r];
  }
}

// ---------- pack int32 ids -> u8 ([t][s] natural layout) ----------
__global__ __launch_bounds__(256) void k_pack(const int* __restrict__ rel, const int* __restrict__ rel_ids,
                                              u8* __restrict__ dst8) {
  int i = (blockIdx.x * 256 + threadIdx.x) * 4;
  const int* src = (i < 4194304) ? (rel + i) : (rel_ids + (i - 4194304));
  int4 v = *(const int4*)src;
  uchar4 o = {(u8)v.x, (u8)v.y, (u8)v.z, (u8)v.w};
  *(uchar4*)(dst8 + i) = o;
}

// ---------- 128x128 bf16 MFMA GEMM, BK=32, double-buffered global_load_lds ----------
template <int EPI>
__global__ __launch_bounds__(256) void k_gemm(
    const bf16* __restrict__ A, const bf16* __restrict__ BT, const float* __restrict__ bias,
    float* __restrict__ outF, bf16* __restrict__ qg, bf16* __restrict__ kg, bf16* __restrict__ vtg,
    int M, int N, int K) {
  __shared__ __align__(16) bf16 Ab[2][128 * 32];
  __shared__ __align__(16) bf16 Bb[2][128 * 32];
  int tid = threadIdx.x, lane = tid & 63, w = tid >> 6;
  int wm = w >> 1, wn = w & 1;
  int m0 = blockIdx.y * 128, n0 = blockIdx.x * 128;
  int sl = lane >> 4, lr = lane & 15;
  f32x4 acc[4][4] = {};
  int NKt = K >> 5;

  auto stage = [&](int kt, int bidx) {
    const bf16* Ag = A + (size_t)m0 * K + kt * 32;
    const bf16* Bg = BT + (size_t)n0 * K + kt * 32;
#pragma unroll
    for (int j = 0; j < 2; ++j) {
      int c = w * 128 + j * 64 + lane;
      int row = c >> 2, slot = c & 3;
      int ss = slot ^ ((row >> 1) & 3);
      gld16(Ag + (size_t)row * K + ss * 8, &Ab[bidx][(w * 128 + j * 64) * 8]);
      gld16(Bg + (size_t)row * K + ss * 8, &Bb[bidx][(w * 128 + j * 64) * 8]);
    }
  };
  stage(0, 0);
  for (int kt = 0; kt < NKt; ++kt) {
    int bidx = kt & 1;
    __syncthreads();
    if (kt + 1 < NKt) stage(kt + 1, bidx ^ 1);
    bf16x8 af[4], bfv[4];
#pragma unroll
    for (int mi = 0; mi < 4; ++mi) {
      int row = wm * 64 + mi * 16 + lr;
      af[mi] = *(const bf16x8*)&Ab[bidx][row * 32 + ((sl ^ ((row >> 1) & 3)) * 8)];
    }
#pragma unroll
    for (int ni = 0; ni < 4; ++ni) {
      int row = wn * 64 + ni * 16 + lr;
      bfv[ni] = *(const bf16x8*)&Bb[bidx][row * 32 + ((sl ^ ((row >> 1) & 3)) * 8)];
    }
#pragma unroll
    for (int mi = 0; mi < 4; ++mi)
#pragma unroll
      for (int ni = 0; ni < 4; ++ni)
        acc[mi][ni] = __builtin_amdgcn_mfma_f32_16x16x32_bf16(af[mi], bfv[ni], acc[mi][ni], 0, 0, 0);
  }
#pragma unroll
  for (int ni = 0; ni < 4; ++ni) {
    int n = n0 + wn * 64 + ni * 16 + lr;
    float bv = bias[n];
#pragma unroll
    for (int mi = 0; mi < 4; ++mi) {
      int mb = m0 + wm * 64 + mi * 16 + sl * 4;
#pragma unroll
      for (int r = 0; r < 4; ++r) {
        float v = acc[mi][ni][r] + bv;
        int m = mb + r;
        if (EPI == 0) {
          int region = n >> 10, hh = (n & 1023) >> 6, d = n & 63;
          int bb = m >> 10, t = m & 1023;
          int bh = bb * NH_ + hh;
          if (region == 0)      qg[((size_t)bh * T_ + t) * HD_ + d] = (bf16)v;
          else if (region == 1) kg[((size_t)bh * T_ + t) * HD_ + d] = (bf16)v;
          else                  vtg[((size_t)bh * HD_ + d) * T_ + t] = (bf16)v;
        } else {
          outF[(size_t)m * N + n] = v;
        }
      }
    }
  }
}

// ---------- wave-independent fused attention, typed-LDS (ds ops guaranteed) ----------
// V=0 full (writes ret). Ablation: V1 no tab/atomics; V2 V1-minus-exp; V3 no P/PV;
// V4 stage-only; V5 compute-only (no in-loop staging). Variants store nothing.
struct MainSm {
  bf16 KB[2][2048];   // K  [32s][64d], slot^=(s&7)
  bf16 VB[2][2048];   // V^T[64d][32s], slot^=(d&3)
  bf16 PB[512];       // P  [16t][32s], slot^=(t&3)
  u8 IDS[2][1024];    // R8[16t][32s] | I8[16t][32s]
  float prel[1024];   // [16t][64] buckets
  float tab[64];
};
struct EpiSm {
  float ob[2048];     // overlays KB: O^T readback [16][68]
  float rvb[2048];    // overlays VB: rel_values half
};
union SmU { MainSm m; EpiSm e; };

template <int V>
__global__ __launch_bounds__(64) void k_attn(
    const bf16* __restrict__ qg, const bf16* __restrict__ kg, const bf16* __restrict__ vtg,
    const u8* __restrict__ rel8, const float* __restrict__ rel_weights,
    const u8* __restrict__ relid8, const float* __restrict__ rel_values,
    bf16* __restrict__ ret) {
  __shared__ __align__(16) SmU sm;

  int bx = blockIdx.x;
  int tt = 63 - (bx & 63);                // heavy strips first
  int h = (bx >> 6) & 15, b = bx >> 10;
  int bh = b * NH_ + h;
  int t0 = tt * 16;
  int lane = threadIdx.x;
  int lr = lane & 15, sl = lane >> 4;

  sm.m.tab[lane] = __expf(rel_weights[lane * NH_ + h]);
#pragma unroll
  for (int i = 0; i < 4; ++i) ((float4*)sm.m.prel)[lane + 64 * i] = float4{0.f, 0.f, 0.f, 0.f};

  // Q fragments (B-operand: col t = lr, k = d)
  const bf16* qrow = qg + ((size_t)bh * T_ + t0 + lr) * HD_;
  bf16x8 qf0 = *(const bf16x8*)(qrow + sl * 8);
  bf16x8 qf1 = *(const bf16x8*)(qrow + 32 + sl * 8);

  const u8* rel8n = rel8 + (size_t)b * T_ * T_;

  // staging lane constants (source pre-swizzled, LDS dest linear: rule 21)
  int krow = lane >> 3;                     // 0..7
  int kss = (lane & 7) ^ krow;              // K d-slot swizzle
  int vd = lane >> 2;                       // 0..15
  int vss = (lane & 3) ^ (vd & 3);          // V s-slot swizzle
  int itl = (lane & 31) >> 1, ihalf = lane & 1;
  const u8* isrc = ((lane < 32) ? rel8n : relid8) + (size_t)(t0 + itl) * T_ + ihalf * 16;

  auto stage = [&](int st, int bidx) {
    int s0 = st * 32;
    const bf16* kb = kg + ((size_t)bh * T_ + s0 + krow) * HD_ + kss * 8;
#pragma unroll
    for (int g = 0; g < 4; ++g)
      gld16(kb + (size_t)(g * 8) * HD_, &sm.m.KB[bidx][g * 512]);
    const bf16* vb = vtg + ((size_t)bh * HD_ + vd) * T_ + s0 + vss * 8;
#pragma unroll
    for (int g = 0; g < 4; ++g)
      gld16(vb + (size_t)(g * 16) * T_, &sm.m.VB[bidx][g * 512]);
    gld16(isrc + s0, &sm.m.IDS[bidx][0]);
  };

  f32x4 acc[4] = {};
  float lsum = 0.f;
  int n = (tt >> 1) + 1;                    // s-tiles of 32 covering s <= t0+15

  stage(0, 0);
  if constexpr (V == 5) {
    stage(0, 1);
    asm volatile("s_waitcnt vmcnt(0)" ::: "memory");
  }
  for (int st = 0; st < n; ++st) {
    int cur = st & 1;
    int s0 = st * 32;
    asm volatile("s_waitcnt lgkmcnt(0)" ::: "memory");
    if constexpr (V != 5) {
      if (st + 1 < n) {
        stage(st + 1, cur ^ 1);
        asm volatile("s_waitcnt vmcnt(9)" ::: "memory");
      } else {
        asm volatile("s_waitcnt vmcnt(0)" ::: "memory");
      }
    }
    __builtin_amdgcn_sched_barrier(0);
    if constexpr (V == 4) continue;

    // S^T = K * Q
    f32x4 S[2] = {};
#pragma unroll
    for (int si = 0; si < 2; ++si) {
      int srow = si * 16 + lr;
#pragma unroll
      for (int dsi = 0; dsi < 2; ++dsi) {
        bf16x8 ka = *(const bf16x8*)&sm.m.KB[cur][srow * 64 + (((dsi * 4 + sl) ^ (lr & 7)) * 8)];
        S[si] = __builtin_amdgcn_mfma_f32_16x16x32_bf16(ka, dsi ? qf1 : qf0, S[si], 0, 0, 0);
      }
    }
    // exp(S/8)*tab[rel], mask, P write, bucket atomics
    int tglob = t0 + lr;
#pragma unroll
    for (int si = 0; si < 2; ++si) {
      int sbase = s0 + si * 16 + sl * 4;
      u32 rid = 0, iid = 0;
      if constexpr (V == 0 || V == 3 || V == 5) {
        rid = *(const u32*)&sm.m.IDS[cur][lr * 32 + si * 16 + sl * 4];
        iid = *(const u32*)&sm.m.IDS[cur][512 + lr * 32 + si * 16 + sl * 4];
      }
      u16 pb4[4];
#pragma unroll
      for (int r = 0; r < 4; ++r) {
        bool on = (sbase + r <= tglob);
        float e;
        if constexpr (V == 2)      e = on ? S[si][r] * 0.125f : 0.f;
        else if constexpr (V == 1) e = on ? __expf(S[si][r] * 0.125f) : 0.f;
        else                       e = on ? __expf(S[si][r] * 0.125f) * sm.m.tab[(rid >> (8 * r)) & 63] : 0.f;
        lsum += e;
        bf16 eb = (bf16)e;
        pb4[r] = *(u16*)&eb;
        if constexpr (V == 0 || V == 3 || V == 5)
          if (e != 0.f) atomicAdd(&sm.m.prel[lr * 64 + ((iid >> (8 * r)) & 63)], e);
      }
      u32 p01 = (u32)pb4[0] | ((u32)pb4[1] << 16);
      u32 p23 = (u32)pb4[2] | ((u32)pb4[3] << 16);
      if constexpr (V == 3) {
        asm volatile("" :: "v"(p01), "v"(p23));
      } else {
        int slot = (si * 2 + (sl >> 1)) ^ (lr & 3);
        *(uint2*)&sm.m.PB[lr * 32 + slot * 8 + (sl & 1) * 4] = uint2{p01, p23};
      }
    }
    // O^T += V^T * P^T
    if constexpr (V != 3) {
      bf16x8 pbf = *(const bf16x8*)&sm.m.PB[lr * 32 + ((sl ^ (lr & 3)) * 8)];
#pragma unroll
      for (int ni = 0; ni < 4; ++ni) {
        int d = ni * 16 + lr;
        bf16x8 va = *(const bf16x8*)&sm.m.VB[cur][d * 32 + ((sl ^ (lr & 3)) * 8)];
        acc[ni] = __builtin_amdgcn_mfma_f32_16x16x32_bf16(va, pbf, acc[ni], 0, 0, 0);
      }
    }
  }

  if constexpr (V != 0) {
    asm volatile("" :: "v"(lsum));
#pragma unroll
    for (int ni = 0; ni < 4; ++ni)
#pragma unroll
      for (int r = 0; r < 4; ++r) asm volatile("" :: "v"(acc[ni][r]));
    return;
  }

  // ---- epilogue (wave-local) ----
  float v = lsum;
  v += __shfl_xor(v, 16);
  v += __shfl_xor(v, 32);
  float inv = 1.f / v;                      // lane lr holds inv for t = lr

  asm volatile("s_waitcnt lgkmcnt(0)" ::: "memory");
  __builtin_amdgcn_sched_barrier(0);
  float* ob = sm.e.ob;                      // [16][68] over KB
#pragma unroll
  for (int ni = 0; ni < 4; ++ni)
#pragma unroll
    for (int r = 0; r < 4; ++r)
      ob[lr * 68 + ni * 16 + sl * 4 + r] = acc[ni][r];

  int th = lane >> 2, q = lane & 3;         // lane owns (t=th, d=q*16..q*16+15)
  f32x4 o[4], racc[4] = {};
#pragma unroll
  for (int i = 0; i < 4; ++i)
    o[i] = *(const f32x4*)&ob[th * 68 + q * 16 + i * 4];
  float invt = __shfl(inv, th);

  float* rvb = sm.e.rvb;                    // over VB
#pragma unroll
  for (int p = 0; p < 2; ++p) {
    asm volatile("s_waitcnt lgkmcnt(0)" ::: "memory");
    __builtin_amdgcn_sched_barrier(0);
#pragma unroll
    for (int g = 0; g < 8; ++g)
      gld16(rel_values + p * 2048 + g * 256 + lane * 4, &rvb[g * 256]);
    asm volatile("s_waitcnt vmcnt(0)" ::: "memory");
    __builtin_amdgcn_sched_barrier(0);
    for (int rr = 0; rr < 32; ++rr) {
      float pv = sm.m.prel[th * 64 + p * 32 + rr];
#pragma unroll
      for (int i = 0; i < 4; ++i)
        racc[i] += pv * *(const f32x4*)&rvb[rr * 64 + q * 16 + i * 4];
    }
  }

  u16 outv[16];
#pragma unroll
  for (int i = 0; i < 4; ++i)
#pragma unroll
    for (int j = 0; j < 4; ++j) {
      bf16 ob16 = (bf16)((o[i][j] + racc[i][j]) * invt);
      outv[i * 4 + j] = *(u16*)&ob16;
    }
  bf16* rp = ret + ((size_t)(b * T_ + t0 + th) * NX_ + h * HD_ + q * 16);
  *(ushort8*)rp = *(ushort8*)&outv[0];
  *(ushort8*)(rp + 8) = *(ushort8*)&outv[8];
}

extern "C" void kernel_launch(void* const* d_in, const int* in_sizes, int n_in,
                              void* d_out, int out_size, void* d_ws, size_t ws_size,
                              hipStream_t stream) {
  const float* x = (const float*)d_in[0];
  const int* rel = (const int*)d_in[1];
  const float* w_attn = (const float*)d_in[2];
  const float* b_attn = (const float*)d_in[3];
  const float* w_proj = (const float*)d_in[4];
  const float* b_proj = (const float*)d_in[5];
  const float* rel_weights = (const float*)d_in[6];
  const float* rel_values = (const float*)d_in[7];
  const int* rel_ids = (const int*)d_in[8];
  float* out = (float*)d_out;

  char* ws = (char*)d_ws;
  bf16* xb  = (bf16*)(ws);                    //  8 MB: x as bf16 (consumed by gemm<0>)
  bf16* wTa = (bf16*)(ws + 8388608);          //  6 MB: w_attn^T
  bf16* wTp = (bf16*)(ws + 14680064);         //  2 MB: w_proj^T
  bf16* qg  = (bf16*)(ws + 16777216);         //  8 MB: q (bh,t,d)
  bf16* kg  = (bf16*)(ws + 25165824);         //  8 MB: k (bh,t,d)
  bf16* vtg = (bf16*)(ws + 33554432);         //  8 MB: v^T (bh,d,t)
  bf16* ret = (bf16*)(ws + 41943040);         //  8 MB: attn out (b,t,nx)
  // packed u8 id planes overlay the dead xb region after gemm<0> consumed it
  u8* rel8   = (u8*)(ws);                     //  4 MB: rel  ids u8, [b][t][s]
  u8* relid8 = (u8*)(ws + 4194304);           //  1 MB: rel_ids u8, [t][s]

  k_cvt<<<4096, 256, 0, stream>>>(x, xb, 4194304);
  k_transpose<<<dim3(48, 16), 256, 0, stream>>>(w_attn, wTa, 1024, 3072);
  k_transpose<<<dim3(16, 16), 256, 0, stream>>>(w_proj, wTp, 1024, 1024);
  k_gemm<0><<<dim3(24, 32), 256, 0, stream>>>(xb, wTa, b_attn, nullptr, qg, kg, vtg, 4096, 3072, 1024);
  k_pack<<<5120, 256, 0, stream>>>(rel, rel_ids, rel8);
  k_attn<0><<<4096, 64, 0, stream>>>(qg, kg, vtg, rel8, rel_weights, relid8, rel_values, ret);
  k_gemm<1><<<dim3(8, 32), 256, 0, stream>>>(ret, wTp, b_proj, out, nullptr, nullptr, nullptr, 4096, 1024, 1024);
  // ---- ablation probes (b=0 slice, no stores; durations read from rocprof) ----
  k_attn<1><<<1024, 64, 0, stream>>>(qg, kg, vtg, rel8, rel_weights, relid8, rel_values, ret);
  k_attn<2><<<1024, 64, 0, stream>>>(qg, kg, vtg, rel8, rel_weights, relid8, rel_values, ret);
  k_attn<3><<<1024, 64, 0, stream>>>(qg, kg, vtg, rel8, rel_weights, relid8, rel_values, ret);
  k_attn<4><<<1024, 64, 0, stream>>>(qg, kg, vtg, rel8, rel_weights, relid8, rel_values, ret);
  k_attn<5><<<1024, 64, 0, stream>>>(qg, kg, vtg, rel8, rel_weights, relid8, rel_values, ret);
}